// Round 2
// baseline (330.735 us; speedup 1.0000x reference)
//
#include <hip/hip_runtime.h>

#define NGROUPS 256

typedef unsigned long long u64;

// Kernel A: grid-stride over float4 chunks; per-block LDS accumulation of
// per-group {pos exp-sum, neg exp-sum, packed counts}; write block partials.
__global__ __launch_bounds__(256) void rrl_accum(
    const float4* __restrict__ x4,
    const int4*   __restrict__ t4,
    const int*    __restrict__ img_id,
    float* __restrict__ pos_part,   // [NB][NGROUPS]
    float* __restrict__ neg_part,   // [NB][NGROUPS]
    u64*   __restrict__ cnt_part,   // [NB][NGROUPS]  (hi32=neg_cnt, lo32=pos_cnt)
    int n4)
{
    __shared__ float s_pos[NGROUPS];
    __shared__ float s_neg[NGROUPS];
    __shared__ u64   s_cnt[NGROUPS];
    for (int i = threadIdx.x; i < NGROUPS; i += 256) {
        s_pos[i] = 0.f; s_neg[i] = 0.f; s_cnt[i] = 0ULL;
    }
    __syncthreads();

    const int stride = gridDim.x * 256;
    for (int i = blockIdx.x * 256 + threadIdx.x; i < n4; i += stride) {
        float4 v = x4[i];
        int4   t = t4[i];
        // C=128 -> 32 float4 per row; all 4 elements share the row's group
        int g = img_id[i >> 5];
        float e0 = __expf(v.x);
        float e1 = __expf(v.y);
        float e2 = __expf(v.z);
        float e3 = __expf(v.w);
        float p = 0.f, q = 0.f; unsigned pc = 0u;
        if (t.x != 0) { p += e0; ++pc; } else { q += e0; }
        if (t.y != 0) { p += e1; ++pc; } else { q += e1; }
        if (t.z != 0) { p += e2; ++pc; } else { q += e2; }
        if (t.w != 0) { p += e3; ++pc; } else { q += e3; }
        atomicAdd(&s_pos[g], p);
        atomicAdd(&s_neg[g], q);
        atomicAdd(&s_cnt[g], ((u64)(4u - pc) << 32) | (u64)pc);
    }
    __syncthreads();

    const int base = blockIdx.x * NGROUPS;
    for (int g = threadIdx.x; g < NGROUPS; g += 256) {
        pos_part[base + g] = s_pos[g];
        neg_part[base + g] = s_neg[g];
        cnt_part[base + g] = s_cnt[g];
    }
}

// Kernel B: one block per group; reduce NB partials in f64, emit loss_g.
__global__ __launch_bounds__(256) void rrl_group(
    const float* __restrict__ pos_part,
    const float* __restrict__ neg_part,
    const u64*   __restrict__ cnt_part,
    double* __restrict__ loss_g,
    int*    __restrict__ pres_g,
    int nb)
{
    const int g = blockIdx.x;
    double ps = 0.0, ns = 0.0;
    u64 c = 0ULL;
    for (int b = threadIdx.x; b < nb; b += 256) {
        ps += (double)pos_part[b * NGROUPS + g];
        ns += (double)neg_part[b * NGROUPS + g];
        c  += cnt_part[b * NGROUPS + g];
    }
    __shared__ double sp[256];
    __shared__ double sn[256];
    __shared__ u64    sc[256];
    sp[threadIdx.x] = ps; sn[threadIdx.x] = ns; sc[threadIdx.x] = c;
    __syncthreads();
    for (int off = 128; off > 0; off >>= 1) {
        if (threadIdx.x < off) {
            sp[threadIdx.x] += sp[threadIdx.x + off];
            sn[threadIdx.x] += sn[threadIdx.x + off];
            sc[threadIdx.x] += sc[threadIdx.x + off];
        }
        __syncthreads();
    }
    if (threadIdx.x == 0) {
        double pos_sum = sp[0];
        double neg_sum = sn[0];
        u64 cc = sc[0];
        long long pc = (long long)(cc & 0xffffffffULL);
        long long nc = (long long)(cc >> 32);
        long long count = pc + nc;
        // Expected sum of the k = min(pc, nc) randomly-sampled negatives:
        // neg_sum * k / nc  (exact when pc >= nc: all negatives selected).
        double sel = 0.0;
        if (nc > 0) {
            long long k = (pc < nc) ? pc : nc;
            sel = neg_sum * ((double)k / (double)nc);
        }
        double loss = 0.0;
        if (pc > 0) {
            double both = pos_sum + sel;
            loss = -log(pos_sum / both);
        }
        loss_g[g] = loss;
        pres_g[g] = (count > 0) ? 1 : 0;
    }
}

// Kernel C: reduce 256 group losses -> scalar.
__global__ __launch_bounds__(256) void rrl_final(
    const double* __restrict__ loss_g,
    const int*    __restrict__ pres_g,
    float* __restrict__ out)
{
    const int t = threadIdx.x;
    __shared__ double sl[256];
    __shared__ int    sp[256];
    sl[t] = loss_g[t];
    sp[t] = pres_g[t];
    __syncthreads();
    for (int off = 128; off > 0; off >>= 1) {
        if (t < off) { sl[t] += sl[t + off]; sp[t] += sp[t + off]; }
        __syncthreads();
    }
    if (t == 0) {
        double npres = (sp[0] > 0) ? (double)sp[0] : 1.0;
        out[0] = (float)(sl[0] / npres);
    }
}

extern "C" void kernel_launch(void* const* d_in, const int* in_sizes, int n_in,
                              void* d_out, int out_size, void* d_ws, size_t ws_size,
                              hipStream_t stream) {
    const float4* x4  = (const float4*)d_in[0];
    const int4*   t4  = (const int4*)d_in[1];
    const int*    img = (const int*)d_in[2];
    float* out = (float*)d_out;

    const int NC = in_sizes[0];       // N * C = 262144 * 128
    const int n4 = NC / 4;            // float4 count (C=128 divisible by 4)

    // Workspace layout: [NB][256] f32 pos, [NB][256] f32 neg, [NB][256] u64 cnt,
    // then 256 f64 loss, 256 i32 present.
    int NB = 1024;
    size_t tail = NGROUPS * (sizeof(double) + sizeof(int));
    while (NB > 64 &&
           (size_t)NB * NGROUPS * (4 + 4 + 8) + tail > ws_size) {
        NB >>= 1;
    }
    char* w = (char*)d_ws;
    float* pos_part = (float*)w;                 w += (size_t)NB * NGROUPS * 4;
    float* neg_part = (float*)w;                 w += (size_t)NB * NGROUPS * 4;
    u64*   cnt_part = (u64*)w;                   w += (size_t)NB * NGROUPS * 8;
    double* loss_g  = (double*)w;                w += NGROUPS * 8;
    int*    pres_g  = (int*)w;

    rrl_accum<<<NB, 256, 0, stream>>>(x4, t4, img, pos_part, neg_part, cnt_part, n4);
    rrl_group<<<NGROUPS, 256, 0, stream>>>(pos_part, neg_part, cnt_part, loss_g, pres_g, NB);
    rrl_final<<<1, 256, 0, stream>>>(loss_g, pres_g, out);
}

// Round 3
// 299.049 us; speedup vs baseline: 1.1060x; 1.1060x over previous
//
#include <hip/hip_runtime.h>

#define NGROUPS 256

typedef unsigned long long u64;

// Kernel A: grid-stride over float4 chunks. Key structure: C=128 floats/row =
// 32 float4 per row, so 32 consecutive threads (a half-wave) share one row and
// therefore one group id. Reduce p/q/counts across the 32-lane half via
// __shfl_xor (masks 1..16 stay within a 32-lane half), then lanes 0 and 32
// issue a single LDS atomic each (different rows -> nearly always different
// groups -> no same-address serialization).
__global__ __launch_bounds__(256) void rrl_accum(
    const float4* __restrict__ x4,
    const int4*   __restrict__ t4,
    const int*    __restrict__ img_id,
    float* __restrict__ pos_part,   // [NGROUPS][NB]  (transposed for coalesced B)
    float* __restrict__ neg_part,   // [NGROUPS][NB]
    u64*   __restrict__ cnt_part,   // [NGROUPS][NB]  (hi32=neg_cnt, lo32=pos_cnt)
    int n4, int nb)
{
    __shared__ float s_pos[NGROUPS];
    __shared__ float s_neg[NGROUPS];
    __shared__ u64   s_cnt[NGROUPS];
    for (int i = threadIdx.x; i < NGROUPS; i += 256) {
        s_pos[i] = 0.f; s_neg[i] = 0.f; s_cnt[i] = 0ULL;
    }
    __syncthreads();

    const int lane31 = threadIdx.x & 31;
    const int stride = gridDim.x * 256;
    for (int i = blockIdx.x * 256 + threadIdx.x; i < n4; i += stride) {
        float4 v = x4[i];
        int4   t = t4[i];
        int g = img_id[i >> 5];          // same for all 32 lanes of the half-wave
        float e0 = __expf(v.x);
        float e1 = __expf(v.y);
        float e2 = __expf(v.z);
        float e3 = __expf(v.w);
        float p = 0.f, q = 0.f;
        int pc = 0, qc = 0;
        if (t.x != 0) { p += e0; ++pc; } else { q += e0; ++qc; }
        if (t.y != 0) { p += e1; ++pc; } else { q += e1; ++qc; }
        if (t.z != 0) { p += e2; ++pc; } else { q += e2; ++qc; }
        if (t.w != 0) { p += e3; ++pc; } else { q += e3; ++qc; }
        int cnt = pc | (qc << 16);       // fields stay < 2^16 after 32-lane sum
        // 32-lane butterfly reduce (masks < 32 never cross the half boundary)
        #pragma unroll
        for (int m = 1; m < 32; m <<= 1) {
            p   += __shfl_xor(p,   m, 64);
            q   += __shfl_xor(q,   m, 64);
            cnt += __shfl_xor(cnt, m, 64);
        }
        if (lane31 == 0) {
            atomicAdd(&s_pos[g], p);
            atomicAdd(&s_neg[g], q);
            atomicAdd(&s_cnt[g], ((u64)(cnt >> 16) << 32) | (u64)(cnt & 0xffff));
        }
    }
    __syncthreads();

    for (int g = threadIdx.x; g < NGROUPS; g += 256) {
        pos_part[(size_t)g * nb + blockIdx.x] = s_pos[g];
        neg_part[(size_t)g * nb + blockIdx.x] = s_neg[g];
        cnt_part[(size_t)g * nb + blockIdx.x] = s_cnt[g];
    }
}

// Kernel B: one block per group; partials are contiguous per group -> coalesced.
__global__ __launch_bounds__(256) void rrl_group(
    const float* __restrict__ pos_part,
    const float* __restrict__ neg_part,
    const u64*   __restrict__ cnt_part,
    double* __restrict__ loss_g,
    int*    __restrict__ pres_g,
    int nb)
{
    const size_t g = blockIdx.x;
    double ps = 0.0, ns = 0.0;
    u64 c = 0ULL;
    for (int b = threadIdx.x; b < nb; b += 256) {
        ps += (double)pos_part[g * nb + b];
        ns += (double)neg_part[g * nb + b];
        c  += cnt_part[g * nb + b];
    }
    __shared__ double sp[256];
    __shared__ double sn[256];
    __shared__ u64    sc[256];
    sp[threadIdx.x] = ps; sn[threadIdx.x] = ns; sc[threadIdx.x] = c;
    __syncthreads();
    for (int off = 128; off > 0; off >>= 1) {
        if (threadIdx.x < off) {
            sp[threadIdx.x] += sp[threadIdx.x + off];
            sn[threadIdx.x] += sn[threadIdx.x + off];
            sc[threadIdx.x] += sc[threadIdx.x + off];
        }
        __syncthreads();
    }
    if (threadIdx.x == 0) {
        double pos_sum = sp[0];
        double neg_sum = sn[0];
        u64 cc = sc[0];
        long long pc = (long long)(cc & 0xffffffffULL);
        long long nc = (long long)(cc >> 32);
        long long count = pc + nc;
        // Expected sum of the k = min(pc, nc) randomly-sampled negatives:
        // neg_sum * k / nc (exact when pc >= nc: all negatives selected).
        double sel = 0.0;
        if (nc > 0) {
            long long k = (pc < nc) ? pc : nc;
            sel = neg_sum * ((double)k / (double)nc);
        }
        double loss = 0.0;
        if (pc > 0) {
            double both = pos_sum + sel;
            loss = -log(pos_sum / both);
        }
        loss_g[g] = loss;
        pres_g[g] = (count > 0) ? 1 : 0;
    }
}

// Kernel C: reduce 256 group losses -> scalar.
__global__ __launch_bounds__(256) void rrl_final(
    const double* __restrict__ loss_g,
    const int*    __restrict__ pres_g,
    float* __restrict__ out)
{
    const int t = threadIdx.x;
    __shared__ double sl[256];
    __shared__ int    sp[256];
    sl[t] = loss_g[t];
    sp[t] = pres_g[t];
    __syncthreads();
    for (int off = 128; off > 0; off >>= 1) {
        if (t < off) { sl[t] += sl[t + off]; sp[t] += sp[t + off]; }
        __syncthreads();
    }
    if (t == 0) {
        double npres = (sp[0] > 0) ? (double)sp[0] : 1.0;
        out[0] = (float)(sl[0] / npres);
    }
}

extern "C" void kernel_launch(void* const* d_in, const int* in_sizes, int n_in,
                              void* d_out, int out_size, void* d_ws, size_t ws_size,
                              hipStream_t stream) {
    const float4* x4  = (const float4*)d_in[0];
    const int4*   t4  = (const int4*)d_in[1];
    const int*    img = (const int*)d_in[2];
    float* out = (float*)d_out;

    const int NC = in_sizes[0];       // N * C = 262144 * 128
    const int n4 = NC / 4;            // float4 count (C=128 divisible by 4)

    // Workspace: [NGROUPS][NB] f32 pos, f32 neg, u64 cnt; then 256 f64 + 256 i32.
    int NB = 2048;                    // 8 blocks/CU on 256 CUs -> full occupancy
    size_t tail = NGROUPS * (sizeof(double) + sizeof(int));
    while (NB > 64 &&
           (size_t)NB * NGROUPS * (4 + 4 + 8) + tail > ws_size) {
        NB >>= 1;
    }
    char* w = (char*)d_ws;
    float* pos_part = (float*)w;                 w += (size_t)NB * NGROUPS * 4;
    float* neg_part = (float*)w;                 w += (size_t)NB * NGROUPS * 4;
    u64*   cnt_part = (u64*)w;                   w += (size_t)NB * NGROUPS * 8;
    double* loss_g  = (double*)w;                w += NGROUPS * 8;
    int*    pres_g  = (int*)w;

    rrl_accum<<<NB, 256, 0, stream>>>(x4, t4, img, pos_part, neg_part, cnt_part, n4, NB);
    rrl_group<<<NGROUPS, 256, 0, stream>>>(pos_part, neg_part, cnt_part, loss_g, pres_g, NB);
    rrl_final<<<1, 256, 0, stream>>>(loss_g, pres_g, out);
}

// Round 5
// 282.407 us; speedup vs baseline: 1.1711x; 1.0589x over previous
//
#include <hip/hip_runtime.h>

#define NGROUPS 256
#define NSHARD  8

typedef unsigned long long u64;

// ---- DPP 32-lane sum (pure VALU, no LDS pipe) ----
// row_shr:1/2/4/8 then row_bcast:15. After the chain, lane 31 holds the sum of
// lanes 0..31 and lane 63 holds the sum of lanes 32..63. bound_ctrl=1 -> invalid
// source lanes contribute 0.
template<int CTRL>
__device__ __forceinline__ float dpp_add_f(float x) {
    int s = __builtin_amdgcn_update_dpp(0, __float_as_int(x), CTRL, 0xF, 0xF, true);
    return x + __int_as_float(s);
}
template<int CTRL>
__device__ __forceinline__ int dpp_add_i(int x) {
    return x + __builtin_amdgcn_update_dpp(0, x, CTRL, 0xF, 0xF, true);
}
__device__ __forceinline__ float half_sum_f(float x) {
    x = dpp_add_f<0x111>(x);   // row_shr:1
    x = dpp_add_f<0x112>(x);   // row_shr:2
    x = dpp_add_f<0x114>(x);   // row_shr:4
    x = dpp_add_f<0x118>(x);   // row_shr:8  -> lane15/31/47/63 = row sums
    x = dpp_add_f<0x142>(x);   // row_bcast:15 -> lane31 = half0 sum, lane63 = half1 sum
    return x;
}
__device__ __forceinline__ int half_sum_i(int x) {
    x = dpp_add_i<0x111>(x);
    x = dpp_add_i<0x112>(x);
    x = dpp_add_i<0x114>(x);
    x = dpp_add_i<0x118>(x);
    x = dpp_add_i<0x142>(x);
    return x;
}

// Zero the sharded global accumulators (re-poisoned to 0xAA before each replay).
__global__ __launch_bounds__(256) void rrl_init(
    float* __restrict__ g_pos, float* __restrict__ g_neg, u64* __restrict__ g_cnt)
{
    for (int i = threadIdx.x; i < NSHARD * NGROUPS; i += 256) {
        g_pos[i] = 0.f; g_neg[i] = 0.f; g_cnt[i] = 0ULL;
    }
}

// Kernel A: grid-stride over float4 chunks. C=128 floats/row = 32 float4/row,
// so each 32-lane half-wave shares one row -> one group id. DPP-reduce
// p/q/counts across the half (VALU only), lanes 31/63 do one LDS atomic each.
// Depth-2 software pipeline on the global loads. Block epilogue: sharded
// global atomicAdd (8 shards kill same-address serialization at L2).
__global__ __launch_bounds__(256) void rrl_accum(
    const float4* __restrict__ x4,
    const int4*   __restrict__ t4,
    const int*    __restrict__ img_id,
    float* __restrict__ g_pos,      // [NSHARD][NGROUPS]
    float* __restrict__ g_neg,      // [NSHARD][NGROUPS]
    u64*   __restrict__ g_cnt,      // [NSHARD][NGROUPS] (hi32=neg, lo32=pos)
    int n4)
{
    __shared__ float s_pos[NGROUPS];
    __shared__ float s_neg[NGROUPS];
    __shared__ u64   s_cnt[NGROUPS];
    for (int i = threadIdx.x; i < NGROUPS; i += 256) {
        s_pos[i] = 0.f; s_neg[i] = 0.f; s_cnt[i] = 0ULL;
    }
    __syncthreads();

    const int lane31  = threadIdx.x & 31;
    const int stride  = gridDim.x * 256;
    const int i0      = blockIdx.x * 256 + threadIdx.x;

    float4 vA, vB; int4 tA, tB; int gA = 0, gB = 0;
    if (i0 < n4)          { vA = x4[i0];          tA = t4[i0];          gA = img_id[i0 >> 5]; }
    if (i0 + stride < n4) { vB = x4[i0 + stride]; tB = t4[i0 + stride]; gB = img_id[(i0 + stride) >> 5]; }

    for (int i = i0; i < n4; i += stride) {
        float4 v = vA; int4 t = tA; int g = gA;
        // rotate pipeline and issue the load two iterations ahead
        vA = vB; tA = tB; gA = gB;
        int inext = i + 2 * stride;
        if (inext < n4) { vB = x4[inext]; tB = t4[inext]; gB = img_id[inext >> 5]; }

        float e0 = __expf(v.x);
        float e1 = __expf(v.y);
        float e2 = __expf(v.z);
        float e3 = __expf(v.w);
        float p = 0.f, q = 0.f;
        int pc = 0, qc = 0;
        if (t.x != 0) { p += e0; ++pc; } else { q += e0; ++qc; }
        if (t.y != 0) { p += e1; ++pc; } else { q += e1; ++qc; }
        if (t.z != 0) { p += e2; ++pc; } else { q += e2; ++qc; }
        if (t.w != 0) { p += e3; ++pc; } else { q += e3; ++qc; }
        int cnt = pc | (qc << 16);            // fields < 2^16 after 32-lane sum

        p   = half_sum_f(p);
        q   = half_sum_f(q);
        cnt = half_sum_i(cnt);

        if (lane31 == 31) {                    // lanes 31 and 63 hold half sums
            atomicAdd(&s_pos[g], p);
            atomicAdd(&s_neg[g], q);
            atomicAdd(&s_cnt[g], ((u64)(unsigned)(cnt >> 16) << 32) | (u64)(cnt & 0xffff));
        }
    }
    __syncthreads();

    const int shard = (blockIdx.x & (NSHARD - 1)) * NGROUPS;
    for (int g = threadIdx.x; g < NGROUPS; g += 256) {
        atomicAdd(&g_pos[shard + g], s_pos[g]);
        atomicAdd(&g_neg[shard + g], s_neg[g]);
        atomicAdd(&g_cnt[shard + g], s_cnt[g]);
    }
}

// Final: one block, 256 threads; thread g merges 8 shards, computes loss_g,
// block-reduces to the scalar.
__global__ __launch_bounds__(256) void rrl_final(
    const float* __restrict__ g_pos,
    const float* __restrict__ g_neg,
    const u64*   __restrict__ g_cnt,
    float* __restrict__ out)
{
    const int g = threadIdx.x;
    double pos_sum = 0.0, neg_sum = 0.0;
    u64 cc = 0ULL;
    #pragma unroll
    for (int s = 0; s < NSHARD; ++s) {
        pos_sum += (double)g_pos[s * NGROUPS + g];
        neg_sum += (double)g_neg[s * NGROUPS + g];
        cc      += g_cnt[s * NGROUPS + g];
    }
    long long pc = (long long)(cc & 0xffffffffULL);
    long long nc = (long long)(cc >> 32);
    long long count = pc + nc;

    // Expected sum of the k = min(pc, nc) randomly-sampled negatives:
    // neg_sum * k / nc (exact when pc >= nc: all negatives selected).
    double sel = 0.0;
    if (nc > 0) {
        long long k = (pc < nc) ? pc : nc;
        sel = neg_sum * ((double)k / (double)nc);
    }
    double loss = 0.0;
    if (pc > 0) loss = -log(pos_sum / (pos_sum + sel));
    int present = (count > 0) ? 1 : 0;

    __shared__ double sl[256];
    __shared__ int    sp[256];
    sl[g] = loss; sp[g] = present;
    __syncthreads();
    for (int off = 128; off > 0; off >>= 1) {
        if (g < off) { sl[g] += sl[g + off]; sp[g] += sp[g + off]; }
        __syncthreads();
    }
    if (g == 0) {
        double npres = (sp[0] > 0) ? (double)sp[0] : 1.0;
        out[0] = (float)(sl[0] / npres);
    }
}

extern "C" void kernel_launch(void* const* d_in, const int* in_sizes, int n_in,
                              void* d_out, int out_size, void* d_ws, size_t ws_size,
                              hipStream_t stream) {
    const float4* x4  = (const float4*)d_in[0];
    const int4*   t4  = (const int4*)d_in[1];
    const int*    img = (const int*)d_in[2];
    float* out = (float*)d_out;

    const int NC = in_sizes[0];       // N * C
    const int n4 = NC / 4;            // float4 count (C=128 divisible by 4)

    // ws: [NSHARD][NGROUPS] f32 pos, f32 neg, u64 cnt  (~32 KB)
    char* w = (char*)d_ws;
    float* g_pos = (float*)w;  w += (size_t)NSHARD * NGROUPS * 4;
    float* g_neg = (float*)w;  w += (size_t)NSHARD * NGROUPS * 4;
    u64*   g_cnt = (u64*)w;

    const int NB = 2048;              // 8 blocks/CU on 256 CUs

    rrl_init <<<1, 256, 0, stream>>>(g_pos, g_neg, g_cnt);
    rrl_accum<<<NB, 256, 0, stream>>>(x4, t4, img, g_pos, g_neg, g_cnt, n4);
    rrl_final<<<1, 256, 0, stream>>>(g_pos, g_neg, g_cnt, out);
}